// Round 3
// baseline (245.895 us; speedup 1.0000x reference)
//
#include <hip/hip_runtime.h>

// SplitEmbedding, two-phase:
//  A) per-token search kernel: tune_ids (4 KB) staged in LDS, binary search,
//     write encoded src row to d_ws.  enc = hit ? cand : (0x40000000 | tok).
//  B) copy kernel: 4 tokens/wave. One int4 broadcast load of 4 encodings,
//     12 independent float4 gather loads, then 12 nontemporal float4 stores.
//     High MLP, single-hop dependence, streaming writes bypass L2.

#define EMBED_DIM   768
#define WAVES_PER_BLOCK 4
#define TOK_PER_WAVE 4
#define TOK_PER_BLOCK (WAVES_PER_BLOCK * TOK_PER_WAVE)   // 16
#define MISS_FLAG 0x40000000

typedef __attribute__((ext_vector_type(4))) float f4;

// ---------------- Kernel A: build encoded row indices ----------------
__global__ __launch_bounds__(256) void build_rows_kernel(
    const int* __restrict__ input_ids, const int* __restrict__ tune_ids,
    int* __restrict__ enc, int num_tokens, int num_tune)
{
    __shared__ int lds_tune[2048];
    const bool use_lds = (num_tune <= 2048);
    if (use_lds) {
        for (int i = threadIdx.x; i < num_tune; i += 256)
            lds_tune[i] = tune_ids[i];
        __syncthreads();
    }
    const int t = blockIdx.x * 256 + threadIdx.x;
    if (t >= num_tokens) return;

    const int tok = input_ids[t];
    const int* tab = use_lds ? lds_tune : tune_ids;
    // upper_bound - 1  ("later duplicates win")
    int lo = 0, hi = num_tune;
    while (lo < hi) {
        const int mid = (lo + hi) >> 1;
        if (tab[mid] <= tok) lo = mid + 1;
        else                 hi = mid;
    }
    const int cand = lo - 1;
    const bool hit = (cand >= 0) && (tab[cand] == tok);
    enc[t] = hit ? cand : (MISS_FLAG | tok);
}

// ---------------- Kernel B: batched gather-copy ----------------
__device__ __forceinline__ const f4* decode(int e, const float* base, const float* train) {
    return (e & MISS_FLAG)
        ? (const f4*)(base  + (size_t)(e & (MISS_FLAG - 1)) * EMBED_DIM)
        : (const f4*)(train + (size_t)e * EMBED_DIM);
}

__global__ __launch_bounds__(256) void copy_rows_kernel(
    const int* __restrict__ enc,
    const float* __restrict__ base_weight, const float* __restrict__ train_weight,
    float* __restrict__ out, int num_tokens)
{
    const int wave = threadIdx.x >> 6;
    const int lane = threadIdx.x & 63;
    const int tb   = (blockIdx.x * WAVES_PER_BLOCK + wave) * TOK_PER_WAVE;
    if (tb >= num_tokens) return;

    if (tb + TOK_PER_WAVE <= num_tokens) {
        // 16 B broadcast load of 4 encodings (tb is a multiple of 4).
        const int4 e4 = *(const int4*)(enc + tb);
        const f4* s0 = decode(e4.x, base_weight, train_weight);
        const f4* s1 = decode(e4.y, base_weight, train_weight);
        const f4* s2 = decode(e4.z, base_weight, train_weight);
        const f4* s3 = decode(e4.w, base_weight, train_weight);

        // Issue all 12 independent gather loads, then all 12 streaming stores.
        f4 v[12];
        #pragma unroll
        for (int c = 0; c < 3; ++c) v[0 * 3 + c] = s0[lane + c * 64];
        #pragma unroll
        for (int c = 0; c < 3; ++c) v[1 * 3 + c] = s1[lane + c * 64];
        #pragma unroll
        for (int c = 0; c < 3; ++c) v[2 * 3 + c] = s2[lane + c * 64];
        #pragma unroll
        for (int c = 0; c < 3; ++c) v[3 * 3 + c] = s3[lane + c * 64];

        #pragma unroll
        for (int t = 0; t < 4; ++t) {
            f4* dst = (f4*)(out + (size_t)(tb + t) * EMBED_DIM);
            #pragma unroll
            for (int c = 0; c < 3; ++c)
                __builtin_nontemporal_store(v[t * 3 + c], dst + lane + c * 64);
        }
    } else {
        // Tail: per-token copy with guard.
        for (int t = tb; t < num_tokens; ++t) {
            const f4* src = decode(enc[t], base_weight, train_weight);
            f4* dst = (f4*)(out + (size_t)t * EMBED_DIM);
            #pragma unroll
            for (int c = 0; c < 3; ++c)
                __builtin_nontemporal_store(src[lane + c * 64], dst + lane + c * 64);
        }
    }
}

extern "C" void kernel_launch(void* const* d_in, const int* in_sizes, int n_in,
                              void* d_out, int out_size, void* d_ws, size_t ws_size,
                              hipStream_t stream) {
    const int*   input_ids    = (const int*)d_in[0];
    const int*   tune_ids     = (const int*)d_in[1];
    const float* base_weight  = (const float*)d_in[2];
    const float* train_weight = (const float*)d_in[3];
    float*       out          = (float*)d_out;
    int*         enc          = (int*)d_ws;         // num_tokens ints

    const int num_tokens = in_sizes[0];   // 32768
    const int num_tune   = in_sizes[1];   // 1024

    const int gridA = (num_tokens + 255) / 256;
    build_rows_kernel<<<gridA, 256, 0, stream>>>(input_ids, tune_ids, enc,
                                                 num_tokens, num_tune);

    const int gridB = (num_tokens + TOK_PER_BLOCK - 1) / TOK_PER_BLOCK;
    copy_rows_kernel<<<gridB, 256, 0, stream>>>(enc, base_weight, train_weight,
                                                out, num_tokens);
}

// Round 4
// 245.054 us; speedup vs baseline: 1.0034x; 1.0034x over previous
//
#include <hip/hip_runtime.h>

// SplitEmbedding, fused single-launch:
//   out[t,:] = (input_ids[t] in tune_ids) ? train_weight[row(t),:] : base_weight[input_ids[t],:]
// tune_ids SORTED (1024); "later duplicates win" == upper_bound - 1.
//
// Block = 256 (4 waves). tune_ids staged in LDS (4 KB). Each wave owns 4
// consecutive tokens: lanes 0-3 binary-search their token in LDS, results
// broadcast by __shfl. Then 12 independent float4 gather loads followed by
// 12 nontemporal float4 stores (streaming write, don't churn L2).

#define EMBED_DIM 768
#define WAVES_PER_BLOCK 4
#define TOK_PER_WAVE 4
#define TOK_PER_BLOCK (WAVES_PER_BLOCK * TOK_PER_WAVE)   // 16
#define MISS_FLAG 0x40000000
#define MAX_TUNE_LDS 1024

typedef __attribute__((ext_vector_type(4))) float f4;

__device__ __forceinline__ const f4* decode(int e, const float* base, const float* train) {
    return (e & MISS_FLAG)
        ? (const f4*)(base  + (size_t)(e & (MISS_FLAG - 1)) * EMBED_DIM)
        : (const f4*)(train + (size_t)e * EMBED_DIM);
}

__global__ __launch_bounds__(256) void split_embedding_fused(
    const int* __restrict__ input_ids,       // [num_tokens]
    const int* __restrict__ tune_ids,        // [num_tune], sorted
    const float* __restrict__ base_weight,   // [VOCAB, EMBED_DIM]
    const float* __restrict__ train_weight,  // [num_tune, EMBED_DIM]
    float* __restrict__ out,                 // [num_tokens, EMBED_DIM]
    int num_tokens, int num_tune)
{
    __shared__ int lds_tune[MAX_TUNE_LDS];
    const bool use_lds = (num_tune <= MAX_TUNE_LDS);
    if (use_lds) {
        for (int i = threadIdx.x; i < num_tune; i += 256)
            lds_tune[i] = tune_ids[i];
    }
    __syncthreads();

    const int wave = threadIdx.x >> 6;
    const int lane = threadIdx.x & 63;
    const int tb   = (blockIdx.x * WAVES_PER_BLOCK + wave) * TOK_PER_WAVE;
    if (tb >= num_tokens) return;

    const int* __restrict__ tab = use_lds ? lds_tune : tune_ids;

    if (tb + TOK_PER_WAVE <= num_tokens) {
        // 16 B broadcast load of this wave's 4 token ids.
        const int4 t4 = *(const int4*)(input_ids + tb);

        // Every lane searches token (lane & 3); lanes 0-3 are authoritative.
        const int my = (lane & 3) == 0 ? t4.x : (lane & 3) == 1 ? t4.y
                     : (lane & 3) == 2 ? t4.z : t4.w;
        int lo = 0, hi = num_tune;
        while (lo < hi) {                 // upper_bound
            const int mid = (lo + hi) >> 1;
            if (tab[mid] <= my) lo = mid + 1;
            else                hi = mid;
        }
        const int cand = lo - 1;
        const bool hit = (cand >= 0) && (tab[cand] == my);
        const int enc  = hit ? cand : (MISS_FLAG | my);

        const int e0 = __shfl(enc, 0), e1 = __shfl(enc, 1);
        const int e2 = __shfl(enc, 2), e3 = __shfl(enc, 3);
        const f4* s0 = decode(e0, base_weight, train_weight);
        const f4* s1 = decode(e1, base_weight, train_weight);
        const f4* s2 = decode(e2, base_weight, train_weight);
        const f4* s3 = decode(e3, base_weight, train_weight);

        // 12 independent gather loads, then 12 streaming stores.
        f4 v[12];
        #pragma unroll
        for (int c = 0; c < 3; ++c) v[0 * 3 + c] = s0[lane + c * 64];
        #pragma unroll
        for (int c = 0; c < 3; ++c) v[1 * 3 + c] = s1[lane + c * 64];
        #pragma unroll
        for (int c = 0; c < 3; ++c) v[2 * 3 + c] = s2[lane + c * 64];
        #pragma unroll
        for (int c = 0; c < 3; ++c) v[3 * 3 + c] = s3[lane + c * 64];

        #pragma unroll
        for (int t = 0; t < 4; ++t) {
            f4* dst = (f4*)(out + (size_t)(tb + t) * EMBED_DIM);
            #pragma unroll
            for (int c = 0; c < 3; ++c)
                __builtin_nontemporal_store(v[t * 3 + c], dst + lane + c * 64);
        }
    } else {
        // Tail: per-token with guard.
        for (int t = tb; t < num_tokens; ++t) {
            const int tok = input_ids[t];
            int lo = 0, hi = num_tune;
            while (lo < hi) {
                const int mid = (lo + hi) >> 1;
                if (tab[mid] <= tok) lo = mid + 1;
                else                 hi = mid;
            }
            const int cand = lo - 1;
            const bool hit = (cand >= 0) && (tab[cand] == tok);
            const f4* src = hit
                ? (const f4*)(train_weight + (size_t)cand * EMBED_DIM)
                : (const f4*)(base_weight  + (size_t)tok  * EMBED_DIM);
            f4* dst = (f4*)(out + (size_t)t * EMBED_DIM);
            #pragma unroll
            for (int c = 0; c < 3; ++c)
                __builtin_nontemporal_store(src[lane + c * 64], dst + lane + c * 64);
        }
    }
}

extern "C" void kernel_launch(void* const* d_in, const int* in_sizes, int n_in,
                              void* d_out, int out_size, void* d_ws, size_t ws_size,
                              hipStream_t stream) {
    const int*   input_ids    = (const int*)d_in[0];
    const int*   tune_ids     = (const int*)d_in[1];
    const float* base_weight  = (const float*)d_in[2];
    const float* train_weight = (const float*)d_in[3];
    float*       out          = (float*)d_out;

    const int num_tokens = in_sizes[0];   // 32768
    const int num_tune   = in_sizes[1];   // 1024

    const int grid = (num_tokens + TOK_PER_BLOCK - 1) / TOK_PER_BLOCK;
    split_embedding_fused<<<grid, 256, 0, stream>>>(
        input_ids, tune_ids, base_weight, train_weight, out, num_tokens, num_tune);
}